// Round 6
// baseline (141.403 us; speedup 1.0000x reference)
//
#include <hip/hip_runtime.h>
#include <math.h>

#define NTOK 2048
#define DDIM 768
#define IDIM 384
#define NEXP 16
#define XS_LD 776        // 768 + 8 pad (ushorts)
#define HS_LD 392        // 384 + 8 pad (ushorts)
#define NRT_MAX 144      // max routed m-tiles (sum ceil(c_e/32) <= 4096/32+15 = 143)
#define NSHT 64          // shared m-tiles (2048/32)
#define NWORK ((NSHT + NRT_MAX) * 6)   // 1248 = 8 * 156
#define CHUNK (NWORK / 8)              // 156
#define ECAP 2048                      // per-expert perm capacity
#define HSHARED (NEXP * ECAP)          // h row offset of shared-expert rows (32768)

// prep grid segmentation
#define ZBLK 1536                      // zero-out blocks
#define CBLK (768 + 288 * 17 + 144 * 17)   // conv blocks = 8112
#define GBLK (NTOK / 4)                // gate blocks = 512

typedef __attribute__((ext_vector_type(8))) short short8;   // 8 bf16 = 4 VGPR
typedef __attribute__((ext_vector_type(4))) float f32x4;    // MFMA C/D

__device__ __forceinline__ unsigned short f2bf(float f) {
    unsigned int u = __float_as_uint(f);
    unsigned int r = (u + 0x7fffu + ((u >> 16) & 1u)) >> 16;   // RNE
    return (unsigned short)r;
}

// ---------------- workspace layout (bytes) ----------------
// 0      cursor[16]  (atomic; == counts after gate)
// 64     p_sum[16]
// 1024   perm_t[16*2048] int   (131072)
// 132096 perm_w[16*2048] f32   (131072)  -> ends 263168
#define WS_XB   1048576u                     // x bf16: 3,145,728
#define WS_W1F  4194304u                     // w1 frag-major: 17*768*768*2 = 20,054,016
#define WS_WDF  24248320u                    // wd frag-major: 17*768*384*2 = 10,027,008
#define WS_H    34275328u                    // h: 34816 rows * 384 * 2 = 26,738,688 (ends ~61 MB)

// 1-block: zero the 128 B of atomic state gate needs.
__global__ __launch_bounds__(64) void init_kernel(int* cursor, float* p_sum) {
    int t = threadIdx.x;
    if (t < 16) { cursor[t] = 0; p_sum[t] = 0.f; }
}

// Mega-prep: [0,ZBLK) zero d_out | [ZBLK,ZBLK+CBLK) fp32->bf16 convs |
// [ZBLK+CBLK, +GBLK) gate softmax/top2 + direct scatter.
__global__ __launch_bounds__(256) void prep_kernel(
    const float* __restrict__ x, const float* __restrict__ gate_w,
    const float* __restrict__ rgw, const float* __restrict__ ruw,
    const float* __restrict__ sgw, const float* __restrict__ suw,
    const float* __restrict__ rdw, const float* __restrict__ sdw,
    float4* __restrict__ out4,
    unsigned short* __restrict__ xb, unsigned short* __restrict__ w1f,
    unsigned short* __restrict__ wdf,
    int* __restrict__ cursor, float* __restrict__ p_sum,
    int* __restrict__ perm_t, float* __restrict__ perm_w) {
    int b = blockIdx.x, tid = threadIdx.x;

    if (b < ZBLK) {                                  // ---- zero d_out ----
        int i = b * 256 + tid;
        if (i < NTOK * DDIM / 4) out4[i] = make_float4(0.f, 0.f, 0.f, 0.f);
        return;
    }
    b -= ZBLK;

    if (b < CBLK) {                                  // ---- conversions ----
        const float* s;
        unsigned short* dst;
        if (b < 768) {
            int i = b * 256 + tid;
            s = x + (size_t)i * 8;
            dst = xb + (size_t)i * 8;
        } else if (b < 768 + 288 * 17) {
            int bb = b - 768;
            int E = bb / 288, bx = bb % 288;
            const float* gsrc = (E == 16) ? sgw : rgw + (size_t)E * (IDIM * DDIM);
            const float* usrc = (E == 16) ? suw : ruw + (size_t)E * (IDIM * DDIM);
            int i = bx * 256 + tid;
            int lane = i & 63;
            int fi = i >> 6;
            int ks = fi % 24, rg = fi / 24;
            int b16 = rg >> 1, gu = rg & 1;
            s = (gu ? usrc : gsrc)
              + (size_t)(b16 * 16 + (lane & 15)) * DDIM + ks * 32 + (lane >> 4) * 8;
            dst = w1f + (size_t)E * (DDIM * DDIM) + (size_t)i * 8;
        } else {
            int bb = b - (768 + 288 * 17);
            int E = bb / 144, bx = bb % 144;
            const float* src = (E == 16) ? sdw : rdw + (size_t)E * (DDIM * IDIM);
            int i = bx * 256 + tid;
            int lane = i & 63;
            int fi = i >> 6;
            int ks = fi % 12, cg = fi / 12;
            s = src + (size_t)(cg * 16 + (lane & 15)) * IDIM + ks * 32 + (lane >> 4) * 8;
            dst = wdf + (size_t)E * (DDIM * IDIM) + (size_t)i * 8;
        }
        float4 v0 = *(const float4*)s, v1 = *(const float4*)(s + 4);
        short8 o;
        o[0]=f2bf(v0.x); o[1]=f2bf(v0.y); o[2]=f2bf(v0.z); o[3]=f2bf(v0.w);
        o[4]=f2bf(v1.x); o[5]=f2bf(v1.y); o[6]=f2bf(v1.z); o[7]=f2bf(v1.w);
        *(short8*)dst = o;
        return;
    }
    b -= CBLK;

    // ---- gate: 4 tokens/block (1 per wave) ----
    __shared__ float p_blk[16];
    if (tid < 16) p_blk[tid] = 0.f;
    __syncthreads();

    int wave = tid >> 6, lane = tid & 63;
    int n = b * 4 + wave;
    int e = lane >> 2, q = lane & 3;
    const float4* xr = (const float4*)(x + (size_t)n * DDIM);
    const float4* wr = (const float4*)(gate_w + (size_t)e * DDIM);
    float s = 0.f;
    #pragma unroll 4
    for (int k = q * 48; k < q * 48 + 48; ++k) {
        float4 a = xr[k], bb = wr[k];
        s += a.x * bb.x + a.y * bb.y + a.z * bb.z + a.w * bb.w;
    }
    s += __shfl_xor(s, 1);
    s += __shfl_xor(s, 2);
    float logit = s * 2.5f;

    float l[16];
    #pragma unroll
    for (int j = 0; j < 16; ++j) l[j] = __shfl(logit, j * 4);

    float m = l[0];
    #pragma unroll
    for (int j = 1; j < 16; ++j) m = fmaxf(m, l[j]);
    float sum = 0.f, sc[16];
    #pragma unroll
    for (int j = 0; j < 16; ++j) { sc[j] = __expf(l[j] - m); sum += sc[j]; }
    float inv = 1.f / sum;
    #pragma unroll
    for (int j = 0; j < 16; ++j) sc[j] *= inv;

    float b0 = -1.f; int i0 = 0;
    #pragma unroll
    for (int j = 0; j < 16; ++j) if (sc[j] > b0) { b0 = sc[j]; i0 = j; }
    float b1 = -1.f; int i1 = 0;
    #pragma unroll
    for (int j = 0; j < 16; ++j) if (j != i0 && sc[j] > b1) { b1 = sc[j]; i1 = j; }
    float rs = 1.f / (b0 + b1);

    if (lane == 0) {
        int p0 = atomicAdd(&cursor[i0], 1);
        perm_t[i0 * ECAP + p0] = n;
        perm_w[i0 * ECAP + p0] = b0 * rs;
        int p1 = atomicAdd(&cursor[i1], 1);
        perm_t[i1 * ECAP + p1] = n;
        perm_w[i1 * ECAP + p1] = b1 * rs;
        #pragma unroll
        for (int j = 0; j < 16; ++j) atomicAdd(&p_blk[j], sc[j]);
    }
    __syncthreads();
    if (tid < 16) atomicAdd(&p_sum[tid], p_blk[tid]);
}

// XCD-bijective swizzle over the NWORK flattened (bx, y) space.
__device__ __forceinline__ void swz_decode(int lid, int& bx, int& y) {
    int wid = (lid & 7) * CHUNK + (lid >> 3);
    bx = wid / 6;
    y = wid - bx * 6;
}

// uniform worklist decode: routed tile index r -> (expert e, within-expert tile t).
// returns false if r beyond total tiles.
__device__ __forceinline__ bool tile_decode(const int* __restrict__ counts,
                                            int r, int& e, int& t, int& cnt) {
    int acc = 0;
    for (int ee = 0; ee < NEXP; ++ee) {
        int c = counts[ee];
        int tiles = (c + 31) >> 5;
        if (r < acc + tiles) { e = ee; t = r - acc; cnt = c; return true; }
        acc += tiles;
    }
    return false;
}

// phase 1: g,u GEMM + fused SiLU -> h. grid NWORK+1 (last block = aux), 256 thr.
__global__ __launch_bounds__(256, 3) void p1_kernel(
    const unsigned short* __restrict__ xb, const unsigned short* __restrict__ w1f,
    const int* __restrict__ counts, const float* __restrict__ p_sum,
    const int* __restrict__ perm_t,
    unsigned short* __restrict__ h, float* __restrict__ out_aux) {
    if (blockIdx.x == NWORK) {                       // ---- aux loss ----
        if (threadIdx.x == 0) {
            float a = 0.f;
            for (int ee = 0; ee < 16; ++ee) a += (float)counts[ee] * p_sum[ee];
            out_aux[0] = a * 16.f / ((float)NTOK * (float)NTOK);
        }
        return;
    }

    __shared__ unsigned short xs[32 * XS_LD];   // 49,664 B
    __shared__ int s_tok[32];

    int tid = threadIdx.x;
    int bx, y;
    swz_decode(blockIdx.x, bx, y);
    int e, hbase;
    if (bx < NSHT) {
        e = 16;
        hbase = HSHARED + bx * 32;
        if (tid < 32) s_tok[tid] = bx * 32 + tid;
    } else {
        int t, cnt;
        if (!tile_decode(counts, bx - NSHT, e, t, cnt)) return;
        hbase = e * ECAP + t * 32;
        if (tid < 32) {
            int slot = t * 32 + tid;
            s_tok[tid] = (slot < cnt) ? perm_t[e * ECAP + slot] : 0;
        }
    }
    __syncthreads();

    for (int c = tid; c < 32 * 96; c += 256) {
        int row = c / 96, off = (c - row * 96) * 8;
        *(short8*)(xs + row * XS_LD + off) =
            *(const short8*)(xb + (size_t)s_tok[row] * DDIM + off);
    }
    __syncthreads();

    int lane = tid & 63, wave = tid >> 6;
    int lr = lane & 15, kg = (lane >> 4) * 8, jrow = (lane >> 4) * 4;

    const unsigned short* pg = w1f + ((((size_t)e * 48 + (y * 8 + wave * 2    )) * 24) * 64 + lane) * 8;
    const unsigned short* pu = w1f + ((((size_t)e * 48 + (y * 8 + wave * 2 + 1)) * 24) * 64 + lane) * 8;

    f32x4 accg0 = (f32x4)0.f, accg1 = (f32x4)0.f, accu0 = (f32x4)0.f, accu1 = (f32x4)0.f;
    for (int ks = 0; ks < 24; ++ks) {
        short8 a0 = *(const short8*)(xs + lr * XS_LD + ks * 32 + kg);
        short8 a1 = *(const short8*)(xs + (16 + lr) * XS_LD + ks * 32 + kg);
        short8 bg = *(const short8*)(pg + (size_t)ks * 512);
        short8 bu = *(const short8*)(pu + (size_t)ks * 512);
        accg0 = __builtin_amdgcn_mfma_f32_16x16x32_bf16(a0, bg, accg0, 0, 0, 0);
        accg1 = __builtin_amdgcn_mfma_f32_16x16x32_bf16(a1, bg, accg1, 0, 0, 0);
        accu0 = __builtin_amdgcn_mfma_f32_16x16x32_bf16(a0, bu, accu0, 0, 0, 0);
        accu1 = __builtin_amdgcn_mfma_f32_16x16x32_bf16(a1, bu, accu1, 0, 0, 0);
    }

    int colg = y * 64 + wave * 16 + lr;
    #pragma unroll
    for (int m = 0; m < 2; ++m) {
        #pragma unroll
        for (int j = 0; j < 4; ++j) {
            int tl = m * 16 + jrow + j;
            float g = m ? accg1[j] : accg0[j];
            float u = m ? accu1[j] : accu0[j];
            float hv = g / (1.f + __expf(-g)) * u;
            h[(size_t)(hbase + tl) * IDIM + colg] = f2bf(hv);
        }
    }
}

// phase 2: out GEMM + weighted atomic accumulate. grid NWORK, 256 thr.
__global__ __launch_bounds__(256, 4) void p2_kernel(
    const unsigned short* __restrict__ h, const unsigned short* __restrict__ wdf,
    const int* __restrict__ counts,
    const int* __restrict__ perm_t, const float* __restrict__ perm_w,
    float* __restrict__ out) {
    __shared__ unsigned short hs[32 * HS_LD];   // 25,088 B
    __shared__ int   s_tok[32];
    __shared__ float s_w[32];

    int tid = threadIdx.x;
    int bx, y;
    swz_decode(blockIdx.x, bx, y);
    int e, hbase;
    if (bx < NSHT) {
        e = 16;
        hbase = HSHARED + bx * 32;
        if (tid < 32) { s_tok[tid] = bx * 32 + tid; s_w[tid] = 1.f; }
    } else {
        int t, cnt;
        if (!tile_decode(counts, bx - NSHT, e, t, cnt)) return;
        hbase = e * ECAP + t * 32;
        if (tid < 32) {
            int slot = t * 32 + tid;
            bool v = slot < cnt;
            s_tok[tid] = v ? perm_t[e * ECAP + slot] : 0;
            s_w[tid]   = v ? perm_w[e * ECAP + slot] : 0.f;
        }
    }
    __syncthreads();

    for (int c = tid; c < 32 * 48; c += 256) {
        int row = c / 48, off = (c - row * 48) * 8;
        *(short8*)(hs + row * HS_LD + off) =
            *(const short8*)(h + (size_t)(hbase + row) * IDIM + off);
    }
    __syncthreads();

    int lane = tid & 63, wave = tid >> 6;
    int lr = lane & 15, kg = (lane >> 4) * 8, jrow = (lane >> 4) * 4;

    const unsigned short* p0 = wdf + ((((size_t)e * 48 + (y * 8 + wave * 2    )) * 12) * 64 + lane) * 8;
    const unsigned short* p1 = wdf + ((((size_t)e * 48 + (y * 8 + wave * 2 + 1)) * 12) * 64 + lane) * 8;

    f32x4 acc00 = (f32x4)0.f, acc01 = (f32x4)0.f, acc10 = (f32x4)0.f, acc11 = (f32x4)0.f;
    for (int ks = 0; ks < 12; ++ks) {
        short8 a0 = *(const short8*)(hs + lr * HS_LD + ks * 32 + kg);
        short8 a1 = *(const short8*)(hs + (16 + lr) * HS_LD + ks * 32 + kg);
        short8 b0 = *(const short8*)(p0 + (size_t)ks * 512);
        short8 b1 = *(const short8*)(p1 + (size_t)ks * 512);
        acc00 = __builtin_amdgcn_mfma_f32_16x16x32_bf16(a0, b0, acc00, 0, 0, 0);
        acc01 = __builtin_amdgcn_mfma_f32_16x16x32_bf16(a1, b0, acc01, 0, 0, 0);
        acc10 = __builtin_amdgcn_mfma_f32_16x16x32_bf16(a0, b1, acc10, 0, 0, 0);
        acc11 = __builtin_amdgcn_mfma_f32_16x16x32_bf16(a1, b1, acc11, 0, 0, 0);
    }

    int col0 = y * 128 + wave * 32 + lr;
    #pragma unroll
    for (int m = 0; m < 2; ++m) {
        #pragma unroll
        for (int j = 0; j < 4; ++j) {
            int tl = m * 16 + jrow + j;
            float w = s_w[tl];
            if (w == 0.f) continue;
            float* orow = out + (size_t)s_tok[tl] * DDIM;
            float v0 = m ? acc01[j] : acc00[j];
            float v1 = m ? acc11[j] : acc10[j];
            atomicAdd(orow + col0,      w * v0);
            atomicAdd(orow + col0 + 16, w * v1);
        }
    }
}

extern "C" void kernel_launch(void* const* d_in, const int* in_sizes, int n_in,
                              void* d_out, int out_size, void* d_ws, size_t ws_size,
                              hipStream_t stream) {
    const float* x      = (const float*)d_in[0];
    const float* gate_w = (const float*)d_in[1];
    const float* sg_w   = (const float*)d_in[2];
    const float* su_w   = (const float*)d_in[3];
    const float* sd_w   = (const float*)d_in[4];
    const float* rg_w   = (const float*)d_in[5];
    const float* ru_w   = (const float*)d_in[6];
    const float* rd_w   = (const float*)d_in[7];
    float* out = (float*)d_out;

    char* ws = (char*)d_ws;
    int*   cursor = (int*)(ws + 0);      // == counts after gate
    float* p_sum  = (float*)(ws + 64);
    int*   perm_t = (int*)(ws + 1024);
    float* perm_w = (float*)(ws + 132096);
    unsigned short* xb  = (unsigned short*)(ws + WS_XB);
    unsigned short* w1f = (unsigned short*)(ws + WS_W1F);
    unsigned short* wdf = (unsigned short*)(ws + WS_WDF);
    unsigned short* hbuf= (unsigned short*)(ws + WS_H);

    init_kernel<<<1, 64, 0, stream>>>(cursor, p_sum);

    prep_kernel<<<ZBLK + CBLK + GBLK, 256, 0, stream>>>(
        x, gate_w, rg_w, ru_w, sg_w, su_w, rd_w, sd_w,
        (float4*)out, xb, w1f, wdf, cursor, p_sum, perm_t, perm_w);

    p1_kernel<<<NWORK + 1, 256, 0, stream>>>(
        xb, w1f, cursor, p_sum, perm_t, hbuf, out + (size_t)NTOK * DDIM);

    p2_kernel<<<NWORK, 256, 0, stream>>>(
        hbuf, wdf, cursor, perm_t, perm_w, out);
}

// Round 7
// 140.271 us; speedup vs baseline: 1.0081x; 1.0081x over previous
//
#include <hip/hip_runtime.h>
#include <math.h>

#define NTOK 2048
#define DDIM 768
#define IDIM 384
#define NEXP 16
#define XS_LD 776        // 768 + 8 pad (ushorts)
#define HS_LD 392        // 384 + 8 pad (ushorts)
#define NRT_MAX 144      // max routed m-tiles
#define NSHT 64          // shared m-tiles (2048/32)
#define NWORK ((NSHT + NRT_MAX) * 6)   // 1248 = 8 * 156
#define CHUNK (NWORK / 8)              // 156
#define ECAP 2048                      // per-expert perm capacity
#define HSHARED (NEXP * ECAP)          // h row offset of shared-expert rows

// convzero grid segmentation
#define ZBLK 1536                      // zero-out blocks
#define CBLK (768 + 288 * 17 + 144 * 17)   // conv blocks = 8112

typedef __attribute__((ext_vector_type(8))) short short8;   // 8 bf16 = 4 VGPR
typedef __attribute__((ext_vector_type(4))) float f32x4;    // MFMA C/D

__device__ __forceinline__ unsigned short f2bf(float f) {
    unsigned int u = __float_as_uint(f);
    unsigned int r = (u + 0x7fffu + ((u >> 16) & 1u)) >> 16;   // RNE
    return (unsigned short)r;
}

// ---------------- workspace layout (bytes) ----------------
// 0      cursor[16]  (atomic; == counts after gate)
// 64     p_sum[16]
// 1024   perm_t[16*2048] int   (131072)
// 132096 perm_w[16*2048] f32   (131072)
#define WS_XB   1048576u
#define WS_W1F  4194304u
#define WS_WDF  24248320u
#define WS_H    34275328u

__global__ __launch_bounds__(64) void init_kernel(int* cursor, float* p_sum) {
    int t = threadIdx.x;
    if (t < 16) { cursor[t] = 0; p_sum[t] = 0.f; }
}

// Standalone gate (own regalloc — no spills): softmax/top2 + direct scatter.
__global__ __launch_bounds__(256) void gate_kernel(
    const float* __restrict__ x, const float* __restrict__ gate_w,
    int* __restrict__ cursor, float* __restrict__ p_sum,
    int* __restrict__ perm_t, float* __restrict__ perm_w) {
    __shared__ float p_blk[16];
    int tid = threadIdx.x;
    if (tid < 16) p_blk[tid] = 0.f;
    __syncthreads();

    int wave = tid >> 6, lane = tid & 63;
    int n = blockIdx.x * 4 + wave;
    int e = lane >> 2, q = lane & 3;
    const float4* xr = (const float4*)(x + (size_t)n * DDIM);
    const float4* wr = (const float4*)(gate_w + (size_t)e * DDIM);
    float s = 0.f;
    #pragma unroll 4
    for (int k = q * 48; k < q * 48 + 48; ++k) {
        float4 a = xr[k], b = wr[k];
        s += a.x * b.x + a.y * b.y + a.z * b.z + a.w * b.w;
    }
    s += __shfl_xor(s, 1);
    s += __shfl_xor(s, 2);
    float logit = s * 2.5f;

    float l[16];
    #pragma unroll
    for (int j = 0; j < 16; ++j) l[j] = __shfl(logit, j * 4);

    float m = l[0];
    #pragma unroll
    for (int j = 1; j < 16; ++j) m = fmaxf(m, l[j]);
    float sum = 0.f, sc[16];
    #pragma unroll
    for (int j = 0; j < 16; ++j) { sc[j] = __expf(l[j] - m); sum += sc[j]; }
    float inv = 1.f / sum;
    #pragma unroll
    for (int j = 0; j < 16; ++j) sc[j] *= inv;

    float b0 = -1.f; int i0 = 0;
    #pragma unroll
    for (int j = 0; j < 16; ++j) if (sc[j] > b0) { b0 = sc[j]; i0 = j; }
    float b1 = -1.f; int i1 = 0;
    #pragma unroll
    for (int j = 0; j < 16; ++j) if (j != i0 && sc[j] > b1) { b1 = sc[j]; i1 = j; }
    float rs = 1.f / (b0 + b1);

    if (lane == 0) {
        int p0 = atomicAdd(&cursor[i0], 1);
        perm_t[i0 * ECAP + p0] = n;
        perm_w[i0 * ECAP + p0] = b0 * rs;
        int p1 = atomicAdd(&cursor[i1], 1);
        perm_t[i1 * ECAP + p1] = n;
        perm_w[i1 * ECAP + p1] = b1 * rs;
        #pragma unroll
        for (int j = 0; j < 16; ++j) atomicAdd(&p_blk[j], sc[j]);
    }
    __syncthreads();
    if (tid < 16) atomicAdd(&p_sum[tid], p_blk[tid]);
}

// Low-VGPR bulk: [0,ZBLK) zero d_out | [ZBLK,+CBLK) fp32->bf16 conversions.
__global__ __launch_bounds__(256) void convzero_kernel(
    const float* __restrict__ x,
    const float* __restrict__ rgw, const float* __restrict__ ruw,
    const float* __restrict__ sgw, const float* __restrict__ suw,
    const float* __restrict__ rdw, const float* __restrict__ sdw,
    float4* __restrict__ out4,
    unsigned short* __restrict__ xb, unsigned short* __restrict__ w1f,
    unsigned short* __restrict__ wdf) {
    int b = blockIdx.x, tid = threadIdx.x;

    if (b < ZBLK) {
        int i = b * 256 + tid;
        if (i < NTOK * DDIM / 4) out4[i] = make_float4(0.f, 0.f, 0.f, 0.f);
        return;
    }
    b -= ZBLK;

    const float* s;
    unsigned short* dst;
    if (b < 768) {
        int i = b * 256 + tid;
        s = x + (size_t)i * 8;
        dst = xb + (size_t)i * 8;
    } else if (b < 768 + 288 * 17) {
        int bb = b - 768;
        int E = bb / 288, bx = bb % 288;
        const float* gsrc = (E == 16) ? sgw : rgw + (size_t)E * (IDIM * DDIM);
        const float* usrc = (E == 16) ? suw : ruw + (size_t)E * (IDIM * DDIM);
        int i = bx * 256 + tid;
        int lane = i & 63;
        int fi = i >> 6;
        int ks = fi % 24, rg = fi / 24;
        int b16 = rg >> 1, gu = rg & 1;
        s = (gu ? usrc : gsrc)
          + (size_t)(b16 * 16 + (lane & 15)) * DDIM + ks * 32 + (lane >> 4) * 8;
        dst = w1f + (size_t)E * (DDIM * DDIM) + (size_t)i * 8;
    } else {
        int bb = b - (768 + 288 * 17);
        int E = bb / 144, bx = bb % 144;
        const float* src = (E == 16) ? sdw : rdw + (size_t)E * (DDIM * IDIM);
        int i = bx * 256 + tid;
        int lane = i & 63;
        int fi = i >> 6;
        int ks = fi % 12, cg = fi / 12;
        s = src + (size_t)(cg * 16 + (lane & 15)) * IDIM + ks * 32 + (lane >> 4) * 8;
        dst = wdf + (size_t)E * (DDIM * IDIM) + (size_t)i * 8;
    }
    float4 v0 = *(const float4*)s, v1 = *(const float4*)(s + 4);
    short8 o;
    o[0]=f2bf(v0.x); o[1]=f2bf(v0.y); o[2]=f2bf(v0.z); o[3]=f2bf(v0.w);
    o[4]=f2bf(v1.x); o[5]=f2bf(v1.y); o[6]=f2bf(v1.z); o[7]=f2bf(v1.w);
    *(short8*)dst = o;
}

// XCD-bijective swizzle over the NWORK flattened (bx, y) space.
__device__ __forceinline__ void swz_decode(int lid, int& bx, int& y) {
    int wid = (lid & 7) * CHUNK + (lid >> 3);
    bx = wid / 6;
    y = wid - bx * 6;
}

// routed tile index r -> (expert e, within-expert tile t, count).
__device__ __forceinline__ bool tile_decode(const int* __restrict__ counts,
                                            int r, int& e, int& t, int& cnt) {
    int acc = 0;
    for (int ee = 0; ee < NEXP; ++ee) {
        int c = counts[ee];
        int tiles = (c + 31) >> 5;
        if (r < acc + tiles) { e = ee; t = r - acc; cnt = c; return true; }
        acc += tiles;
    }
    return false;
}

// phase 1: g,u GEMM + fused SiLU -> h. grid NWORK+1 (last block = aux), 256 thr.
__global__ __launch_bounds__(256, 3) void p1_kernel(
    const unsigned short* __restrict__ xb, const unsigned short* __restrict__ w1f,
    const int* __restrict__ counts, const float* __restrict__ p_sum,
    const int* __restrict__ perm_t,
    unsigned short* __restrict__ h, float* __restrict__ out_aux) {
    if (blockIdx.x == NWORK) {
        if (threadIdx.x == 0) {
            float a = 0.f;
            for (int ee = 0; ee < 16; ++ee) a += (float)counts[ee] * p_sum[ee];
            out_aux[0] = a * 16.f / ((float)NTOK * (float)NTOK);
        }
        return;
    }

    __shared__ unsigned short xs[32 * XS_LD];
    __shared__ int s_tok[32];

    int tid = threadIdx.x;
    int bx, y;
    swz_decode(blockIdx.x, bx, y);
    int e, hbase;
    if (bx < NSHT) {
        e = 16;
        hbase = HSHARED + bx * 32;
        if (tid < 32) s_tok[tid] = bx * 32 + tid;
    } else {
        int t, cnt;
        if (!tile_decode(counts, bx - NSHT, e, t, cnt)) return;
        hbase = e * ECAP + t * 32;
        if (tid < 32) {
            int slot = t * 32 + tid;
            s_tok[tid] = (slot < cnt) ? perm_t[e * ECAP + slot] : 0;
        }
    }
    __syncthreads();

    for (int c = tid; c < 32 * 96; c += 256) {
        int row = c / 96, off = (c - row * 96) * 8;
        *(short8*)(xs + row * XS_LD + off) =
            *(const short8*)(xb + (size_t)s_tok[row] * DDIM + off);
    }
    __syncthreads();

    int lane = tid & 63, wave = tid >> 6;
    int lr = lane & 15, kg = (lane >> 4) * 8, jrow = (lane >> 4) * 4;

    const unsigned short* pg = w1f + ((((size_t)e * 48 + (y * 8 + wave * 2    )) * 24) * 64 + lane) * 8;
    const unsigned short* pu = w1f + ((((size_t)e * 48 + (y * 8 + wave * 2 + 1)) * 24) * 64 + lane) * 8;

    f32x4 accg0 = (f32x4)0.f, accg1 = (f32x4)0.f, accu0 = (f32x4)0.f, accu1 = (f32x4)0.f;
    for (int ks = 0; ks < 24; ++ks) {
        short8 a0 = *(const short8*)(xs + lr * XS_LD + ks * 32 + kg);
        short8 a1 = *(const short8*)(xs + (16 + lr) * XS_LD + ks * 32 + kg);
        short8 bg = *(const short8*)(pg + (size_t)ks * 512);
        short8 bu = *(const short8*)(pu + (size_t)ks * 512);
        accg0 = __builtin_amdgcn_mfma_f32_16x16x32_bf16(a0, bg, accg0, 0, 0, 0);
        accg1 = __builtin_amdgcn_mfma_f32_16x16x32_bf16(a1, bg, accg1, 0, 0, 0);
        accu0 = __builtin_amdgcn_mfma_f32_16x16x32_bf16(a0, bu, accu0, 0, 0, 0);
        accu1 = __builtin_amdgcn_mfma_f32_16x16x32_bf16(a1, bu, accu1, 0, 0, 0);
    }

    int colg = y * 64 + wave * 16 + lr;
    #pragma unroll
    for (int m = 0; m < 2; ++m) {
        #pragma unroll
        for (int j = 0; j < 4; ++j) {
            int tl = m * 16 + jrow + j;
            float g = m ? accg1[j] : accg0[j];
            float u = m ? accu1[j] : accu0[j];
            float hv = g / (1.f + __expf(-g)) * u;
            h[(size_t)(hbase + tl) * IDIM + colg] = f2bf(hv);
        }
    }
}

// phase 2: out GEMM + weighted atomic accumulate. grid NWORK, 256 thr.
__global__ __launch_bounds__(256, 4) void p2_kernel(
    const unsigned short* __restrict__ h, const unsigned short* __restrict__ wdf,
    const int* __restrict__ counts,
    const int* __restrict__ perm_t, const float* __restrict__ perm_w,
    float* __restrict__ out) {
    __shared__ unsigned short hs[32 * HS_LD];
    __shared__ int   s_tok[32];
    __shared__ float s_w[32];

    int tid = threadIdx.x;
    int bx, y;
    swz_decode(blockIdx.x, bx, y);
    int e, hbase;
    if (bx < NSHT) {
        e = 16;
        hbase = HSHARED + bx * 32;
        if (tid < 32) { s_tok[tid] = bx * 32 + tid; s_w[tid] = 1.f; }
    } else {
        int t, cnt;
        if (!tile_decode(counts, bx - NSHT, e, t, cnt)) return;
        hbase = e * ECAP + t * 32;
        if (tid < 32) {
            int slot = t * 32 + tid;
            bool v = slot < cnt;
            s_tok[tid] = v ? perm_t[e * ECAP + slot] : 0;
            s_w[tid]   = v ? perm_w[e * ECAP + slot] : 0.f;
        }
    }
    __syncthreads();

    for (int c = tid; c < 32 * 48; c += 256) {
        int row = c / 48, off = (c - row * 48) * 8;
        *(short8*)(hs + row * HS_LD + off) =
            *(const short8*)(h + (size_t)(hbase + row) * IDIM + off);
    }
    __syncthreads();

    int lane = tid & 63, wave = tid >> 6;
    int lr = lane & 15, kg = (lane >> 4) * 8, jrow = (lane >> 4) * 4;

    const unsigned short* p0 = wdf + ((((size_t)e * 48 + (y * 8 + wave * 2    )) * 12) * 64 + lane) * 8;
    const unsigned short* p1 = wdf + ((((size_t)e * 48 + (y * 8 + wave * 2 + 1)) * 12) * 64 + lane) * 8;

    f32x4 acc00 = (f32x4)0.f, acc01 = (f32x4)0.f, acc10 = (f32x4)0.f, acc11 = (f32x4)0.f;
    for (int ks = 0; ks < 12; ++ks) {
        short8 a0 = *(const short8*)(hs + lr * HS_LD + ks * 32 + kg);
        short8 a1 = *(const short8*)(hs + (16 + lr) * HS_LD + ks * 32 + kg);
        short8 b0 = *(const short8*)(p0 + (size_t)ks * 512);
        short8 b1 = *(const short8*)(p1 + (size_t)ks * 512);
        acc00 = __builtin_amdgcn_mfma_f32_16x16x32_bf16(a0, b0, acc00, 0, 0, 0);
        acc01 = __builtin_amdgcn_mfma_f32_16x16x32_bf16(a1, b0, acc01, 0, 0, 0);
        acc10 = __builtin_amdgcn_mfma_f32_16x16x32_bf16(a0, b1, acc10, 0, 0, 0);
        acc11 = __builtin_amdgcn_mfma_f32_16x16x32_bf16(a1, b1, acc11, 0, 0, 0);
    }

    int col0 = y * 128 + wave * 32 + lr;
    #pragma unroll
    for (int m = 0; m < 2; ++m) {
        #pragma unroll
        for (int j = 0; j < 4; ++j) {
            int tl = m * 16 + jrow + j;
            float w = s_w[tl];
            if (w == 0.f) continue;
            float* orow = out + (size_t)s_tok[tl] * DDIM;
            float v0 = m ? acc01[j] : acc00[j];
            float v1 = m ? acc11[j] : acc10[j];
            atomicAdd(orow + col0,      w * v0);
            atomicAdd(orow + col0 + 16, w * v1);
        }
    }
}

extern "C" void kernel_launch(void* const* d_in, const int* in_sizes, int n_in,
                              void* d_out, int out_size, void* d_ws, size_t ws_size,
                              hipStream_t stream) {
    const float* x      = (const float*)d_in[0];
    const float* gate_w = (const float*)d_in[1];
    const float* sg_w   = (const float*)d_in[2];
    const float* su_w   = (const float*)d_in[3];
    const float* sd_w   = (const float*)d_in[4];
    const float* rg_w   = (const float*)d_in[5];
    const float* ru_w   = (const float*)d_in[6];
    const float* rd_w   = (const float*)d_in[7];
    float* out = (float*)d_out;

    char* ws = (char*)d_ws;
    int*   cursor = (int*)(ws + 0);      // == counts after gate
    float* p_sum  = (float*)(ws + 64);
    int*   perm_t = (int*)(ws + 1024);
    float* perm_w = (float*)(ws + 132096);
    unsigned short* xb  = (unsigned short*)(ws + WS_XB);
    unsigned short* w1f = (unsigned short*)(ws + WS_W1F);
    unsigned short* wdf = (unsigned short*)(ws + WS_WDF);
    unsigned short* hbuf= (unsigned short*)(ws + WS_H);

    init_kernel<<<1, 64, 0, stream>>>(cursor, p_sum);

    gate_kernel<<<NTOK / 4, 256, 0, stream>>>(x, gate_w, cursor, p_sum, perm_t, perm_w);

    convzero_kernel<<<ZBLK + CBLK, 256, 0, stream>>>(
        x, rg_w, ru_w, sg_w, su_w, rd_w, sd_w,
        (float4*)out, xb, w1f, wdf);

    p1_kernel<<<NWORK + 1, 256, 0, stream>>>(
        xb, w1f, cursor, p_sum, perm_t, hbuf, out + (size_t)NTOK * DDIM);

    p2_kernel<<<NWORK, 256, 0, stream>>>(
        hbuf, wdf, cursor, perm_t, perm_w, out);
}

// Round 8
// 104.988 us; speedup vs baseline: 1.3469x; 1.3361x over previous
//
#include <hip/hip_runtime.h>
#include <math.h>

#define NTOK 2048
#define DDIM 768
#define IDIM 384
#define NEXP 16
#define XS_LD 776        // 768 + 8 pad (ushorts)
#define HS_LD 392        // 384 + 8 pad (ushorts)
#define NRT_MAX 144      // max routed m-tiles
#define NSHT 64          // shared m-tiles (2048/32)
#define NWORK ((NSHT + NRT_MAX) * 6)   // 1248 = 8 * 156
#define CHUNK (NWORK / 8)              // 156
#define ECAP 2048                      // per-expert perm capacity
#define HSHARED (NEXP * ECAP)          // h row offset of shared-expert rows
#define GBLK (NTOK / 4)                // gate blocks = 512

// convzero grid segmentation
#define ZBLK 1536                      // zero-out blocks
#define CBLK (768 + 288 * 17 + 144 * 17)   // conv blocks = 8112

typedef __attribute__((ext_vector_type(8))) short short8;   // 8 bf16 = 4 VGPR
typedef __attribute__((ext_vector_type(4))) float f32x4;    // MFMA C/D

__device__ __forceinline__ unsigned short f2bf(float f) {
    unsigned int u = __float_as_uint(f);
    unsigned int r = (u + 0x7fffu + ((u >> 16) & 1u)) >> 16;   // RNE
    return (unsigned short)r;
}

// ---------------- workspace layout (bytes) ----------------
// 0      counts[16]
// 1024   perm_t[16*2048] int   (131072) -> 132096
// 132096 perm_w[16*2048] f32   (131072) -> 263168
// 263168 p_partial[512*16] f32 (32768)  -> 295936
// 295936 topk_i[2048*2] int    (16384)  -> 312320
// 312320 topk_w[2048*2] f32    (16384)  -> 328704
#define WS_XB   1048576u
#define WS_W1F  4194304u
#define WS_WDF  24248320u
#define WS_H    34275328u

// Gate: shuffle-only softmax/top2 (no per-lane arrays -> no spill, no global atomics).
// Wave = 1 token; lane = e*4+q; expert e's logit lives (replicated) in its 4 lanes.
__global__ __launch_bounds__(256) void gate_kernel(
    const float* __restrict__ x, const float* __restrict__ gate_w,
    int* __restrict__ topk_i, float* __restrict__ topk_w,
    float* __restrict__ p_partial) {
    __shared__ float p_blk[16];
    int tid = threadIdx.x;
    if (tid < 16) p_blk[tid] = 0.f;
    __syncthreads();

    int wave = tid >> 6, lane = tid & 63;
    int n = blockIdx.x * 4 + wave;
    int e = lane >> 2, q = lane & 3;
    const float4* xr = (const float4*)(x + (size_t)n * DDIM);
    const float4* wr = (const float4*)(gate_w + (size_t)e * DDIM);
    float s = 0.f;
    #pragma unroll 4
    for (int k = q * 48; k < q * 48 + 48; ++k) {
        float4 a = xr[k], b = wr[k];
        s += a.x * b.x + a.y * b.y + a.z * b.z + a.w * b.w;
    }
    s += __shfl_xor(s, 1);
    s += __shfl_xor(s, 2);
    float logit = s * 2.5f;          // all 4 lanes of group e hold expert e's logit

    // softmax over 16 experts via butterfly on lane bits 2..5
    float m = logit;
    #pragma unroll
    for (int mask = 4; mask < 64; mask <<= 1)
        m = fmaxf(m, __shfl_xor(m, mask));
    float ex = __expf(logit - m);
    float sum = ex;
    #pragma unroll
    for (int mask = 4; mask < 64; mask <<= 1)
        sum += __shfl_xor(sum, mask);
    float sc = ex / sum;             // this expert's softmax score

    // top-1 (max, first-index tie-break)
    float v = sc; int idx = e;
    #pragma unroll
    for (int mask = 4; mask < 64; mask <<= 1) {
        float ov = __shfl_xor(v, mask);
        int   oi = __shfl_xor(idx, mask);
        if (ov > v || (ov == v && oi < idx)) { v = ov; idx = oi; }
    }
    float b0 = v; int i0 = idx;
    // top-2: mask out winner, reduce again
    v = (e == i0) ? -1.f : sc; idx = e;
    #pragma unroll
    for (int mask = 4; mask < 64; mask <<= 1) {
        float ov = __shfl_xor(v, mask);
        int   oi = __shfl_xor(idx, mask);
        if (ov > v || (ov == v && oi < idx)) { v = ov; idx = oi; }
    }
    float b1 = v; int i1 = idx;
    float rs = 1.f / (b0 + b1);

    if (lane == 0) {
        topk_i[n * 2] = i0; topk_i[n * 2 + 1] = i1;
        topk_w[n * 2] = b0 * rs; topk_w[n * 2 + 1] = b1 * rs;
    }
    if (q == 0) atomicAdd(&p_blk[e], sc);   // LDS only
    __syncthreads();
    if (tid < 16) p_partial[blockIdx.x * 16 + tid] = p_blk[tid];
}

// Single block: p_partial reduce + counts + aux + LDS-cursor scatter.
__global__ __launch_bounds__(256) void route_kernel(
    const int* __restrict__ topk_i, const float* __restrict__ topk_w,
    const float* __restrict__ p_partial,
    int* __restrict__ counts, int* __restrict__ perm_t, float* __restrict__ perm_w,
    float* __restrict__ out_aux) {
    __shared__ float s_p[256];
    __shared__ float s_psum[16];
    __shared__ int s_cnt[16];
    __shared__ int s_cur[16];
    int tid = threadIdx.x;
    {
        int e = tid & 15, g = tid >> 4;
        float acc = 0.f;
        for (int b = g; b < GBLK; b += 16) acc += p_partial[b * 16 + e];
        s_p[tid] = acc;
    }
    if (tid < 16) { s_cnt[tid] = 0; s_cur[tid] = 0; }
    __syncthreads();
    if (tid < 16) {
        float a = 0.f;
        #pragma unroll
        for (int g = 0; g < 16; ++g) a += s_p[g * 16 + tid];
        s_psum[tid] = a;
    }
    for (int n = tid; n < NTOK; n += 256) {
        atomicAdd(&s_cnt[topk_i[n * 2]], 1);
        atomicAdd(&s_cnt[topk_i[n * 2 + 1]], 1);
    }
    __syncthreads();
    if (tid < 16) counts[tid] = s_cnt[tid];
    if (tid == 0) {
        float a = 0.f;
        for (int e = 0; e < 16; ++e) a += (float)s_cnt[e] * s_psum[e];
        out_aux[0] = a * 16.f / ((float)NTOK * (float)NTOK);
    }
    for (int n = tid; n < NTOK; n += 256) {
        #pragma unroll
        for (int k = 0; k < 2; ++k) {
            int e = topk_i[n * 2 + k];
            int pos = atomicAdd(&s_cur[e], 1);
            perm_t[e * ECAP + pos] = n;
            perm_w[e * ECAP + pos] = topk_w[n * 2 + k];
        }
    }
}

// Low-VGPR bulk: [0,ZBLK) zero d_out | [ZBLK,+CBLK) fp32->bf16 conversions.
__global__ __launch_bounds__(256) void convzero_kernel(
    const float* __restrict__ x,
    const float* __restrict__ rgw, const float* __restrict__ ruw,
    const float* __restrict__ sgw, const float* __restrict__ suw,
    const float* __restrict__ rdw, const float* __restrict__ sdw,
    float4* __restrict__ out4,
    unsigned short* __restrict__ xb, unsigned short* __restrict__ w1f,
    unsigned short* __restrict__ wdf) {
    int b = blockIdx.x, tid = threadIdx.x;

    if (b < ZBLK) {
        int i = b * 256 + tid;
        if (i < NTOK * DDIM / 4) out4[i] = make_float4(0.f, 0.f, 0.f, 0.f);
        return;
    }
    b -= ZBLK;

    const float* s;
    unsigned short* dst;
    if (b < 768) {
        int i = b * 256 + tid;
        s = x + (size_t)i * 8;
        dst = xb + (size_t)i * 8;
    } else if (b < 768 + 288 * 17) {
        int bb = b - 768;
        int E = bb / 288, bx = bb % 288;
        const float* gsrc = (E == 16) ? sgw : rgw + (size_t)E * (IDIM * DDIM);
        const float* usrc = (E == 16) ? suw : ruw + (size_t)E * (IDIM * DDIM);
        int i = bx * 256 + tid;
        int lane = i & 63;
        int fi = i >> 6;
        int ks = fi % 24, rg = fi / 24;
        int b16 = rg >> 1, gu = rg & 1;
        s = (gu ? usrc : gsrc)
          + (size_t)(b16 * 16 + (lane & 15)) * DDIM + ks * 32 + (lane >> 4) * 8;
        dst = w1f + (size_t)E * (DDIM * DDIM) + (size_t)i * 8;
    } else {
        int bb = b - (768 + 288 * 17);
        int E = bb / 144, bx = bb % 144;
        const float* src = (E == 16) ? sdw : rdw + (size_t)E * (DDIM * IDIM);
        int i = bx * 256 + tid;
        int lane = i & 63;
        int fi = i >> 6;
        int ks = fi % 12, cg = fi / 12;
        s = src + (size_t)(cg * 16 + (lane & 15)) * IDIM + ks * 32 + (lane >> 4) * 8;
        dst = wdf + (size_t)E * (DDIM * IDIM) + (size_t)i * 8;
    }
    float4 v0 = *(const float4*)s, v1 = *(const float4*)(s + 4);
    short8 o;
    o[0]=f2bf(v0.x); o[1]=f2bf(v0.y); o[2]=f2bf(v0.z); o[3]=f2bf(v0.w);
    o[4]=f2bf(v1.x); o[5]=f2bf(v1.y); o[6]=f2bf(v1.z); o[7]=f2bf(v1.w);
    *(short8*)dst = o;
}

// XCD-bijective swizzle over the NWORK flattened (bx, y) space.
__device__ __forceinline__ void swz_decode(int lid, int& bx, int& y) {
    int wid = (lid & 7) * CHUNK + (lid >> 3);
    bx = wid / 6;
    y = wid - bx * 6;
}

// routed tile index r -> (expert e, within-expert tile t, count).
__device__ __forceinline__ bool tile_decode(const int* __restrict__ counts,
                                            int r, int& e, int& t, int& cnt) {
    int acc = 0;
    for (int ee = 0; ee < NEXP; ++ee) {
        int c = counts[ee];
        int tiles = (c + 31) >> 5;
        if (r < acc + tiles) { e = ee; t = r - acc; cnt = c; return true; }
        acc += tiles;
    }
    return false;
}

// phase 1: g,u GEMM + fused SiLU -> h. grid NWORK, 256 thr.
__global__ __launch_bounds__(256, 3) void p1_kernel(
    const unsigned short* __restrict__ xb, const unsigned short* __restrict__ w1f,
    const int* __restrict__ counts, const int* __restrict__ perm_t,
    unsigned short* __restrict__ h) {
    __shared__ unsigned short xs[32 * XS_LD];
    __shared__ int s_tok[32];

    int tid = threadIdx.x;
    int bx, y;
    swz_decode(blockIdx.x, bx, y);
    int e, hbase;
    if (bx < NSHT) {
        e = 16;
        hbase = HSHARED + bx * 32;
        if (tid < 32) s_tok[tid] = bx * 32 + tid;
    } else {
        int t, cnt;
        if (!tile_decode(counts, bx - NSHT, e, t, cnt)) return;
        hbase = e * ECAP + t * 32;
        if (tid < 32) {
            int slot = t * 32 + tid;
            s_tok[tid] = (slot < cnt) ? perm_t[e * ECAP + slot] : 0;
        }
    }
    __syncthreads();

    for (int c = tid; c < 32 * 96; c += 256) {
        int row = c / 96, off = (c - row * 96) * 8;
        *(short8*)(xs + row * XS_LD + off) =
            *(const short8*)(xb + (size_t)s_tok[row] * DDIM + off);
    }
    __syncthreads();

    int lane = tid & 63, wave = tid >> 6;
    int lr = lane & 15, kg = (lane >> 4) * 8, jrow = (lane >> 4) * 4;

    const unsigned short* pg = w1f + ((((size_t)e * 48 + (y * 8 + wave * 2    )) * 24) * 64 + lane) * 8;
    const unsigned short* pu = w1f + ((((size_t)e * 48 + (y * 8 + wave * 2 + 1)) * 24) * 64 + lane) * 8;

    f32x4 accg0 = (f32x4)0.f, accg1 = (f32x4)0.f, accu0 = (f32x4)0.f, accu1 = (f32x4)0.f;
    for (int ks = 0; ks < 24; ++ks) {
        short8 a0 = *(const short8*)(xs + lr * XS_LD + ks * 32 + kg);
        short8 a1 = *(const short8*)(xs + (16 + lr) * XS_LD + ks * 32 + kg);
        short8 bg = *(const short8*)(pg + (size_t)ks * 512);
        short8 bu = *(const short8*)(pu + (size_t)ks * 512);
        accg0 = __builtin_amdgcn_mfma_f32_16x16x32_bf16(a0, bg, accg0, 0, 0, 0);
        accg1 = __builtin_amdgcn_mfma_f32_16x16x32_bf16(a1, bg, accg1, 0, 0, 0);
        accu0 = __builtin_amdgcn_mfma_f32_16x16x32_bf16(a0, bu, accu0, 0, 0, 0);
        accu1 = __builtin_amdgcn_mfma_f32_16x16x32_bf16(a1, bu, accu1, 0, 0, 0);
    }

    int colg = y * 64 + wave * 16 + lr;
    #pragma unroll
    for (int m = 0; m < 2; ++m) {
        #pragma unroll
        for (int j = 0; j < 4; ++j) {
            int tl = m * 16 + jrow + j;
            float g = m ? accg1[j] : accg0[j];
            float u = m ? accu1[j] : accu0[j];
            float hv = g / (1.f + __expf(-g)) * u;
            h[(size_t)(hbase + tl) * IDIM + colg] = f2bf(hv);
        }
    }
}

// phase 2: out GEMM + weighted atomic accumulate. grid NWORK, 256 thr.
__global__ __launch_bounds__(256, 4) void p2_kernel(
    const unsigned short* __restrict__ h, const unsigned short* __restrict__ wdf,
    const int* __restrict__ counts,
    const int* __restrict__ perm_t, const float* __restrict__ perm_w,
    float* __restrict__ out) {
    __shared__ unsigned short hs[32 * HS_LD];
    __shared__ int   s_tok[32];
    __shared__ float s_w[32];

    int tid = threadIdx.x;
    int bx, y;
    swz_decode(blockIdx.x, bx, y);
    int e, hbase;
    if (bx < NSHT) {
        e = 16;
        hbase = HSHARED + bx * 32;
        if (tid < 32) { s_tok[tid] = bx * 32 + tid; s_w[tid] = 1.f; }
    } else {
        int t, cnt;
        if (!tile_decode(counts, bx - NSHT, e, t, cnt)) return;
        hbase = e * ECAP + t * 32;
        if (tid < 32) {
            int slot = t * 32 + tid;
            bool v = slot < cnt;
            s_tok[tid] = v ? perm_t[e * ECAP + slot] : 0;
            s_w[tid]   = v ? perm_w[e * ECAP + slot] : 0.f;
        }
    }
    __syncthreads();

    for (int c = tid; c < 32 * 48; c += 256) {
        int row = c / 48, off = (c - row * 48) * 8;
        *(short8*)(hs + row * HS_LD + off) =
            *(const short8*)(h + (size_t)(hbase + row) * IDIM + off);
    }
    __syncthreads();

    int lane = tid & 63, wave = tid >> 6;
    int lr = lane & 15, kg = (lane >> 4) * 8, jrow = (lane >> 4) * 4;

    const unsigned short* p0 = wdf + ((((size_t)e * 48 + (y * 8 + wave * 2    )) * 12) * 64 + lane) * 8;
    const unsigned short* p1 = wdf + ((((size_t)e * 48 + (y * 8 + wave * 2 + 1)) * 12) * 64 + lane) * 8;

    f32x4 acc00 = (f32x4)0.f, acc01 = (f32x4)0.f, acc10 = (f32x4)0.f, acc11 = (f32x4)0.f;
    for (int ks = 0; ks < 12; ++ks) {
        short8 a0 = *(const short8*)(hs + lr * HS_LD + ks * 32 + kg);
        short8 a1 = *(const short8*)(hs + (16 + lr) * HS_LD + ks * 32 + kg);
        short8 b0 = *(const short8*)(p0 + (size_t)ks * 512);
        short8 b1 = *(const short8*)(p1 + (size_t)ks * 512);
        acc00 = __builtin_amdgcn_mfma_f32_16x16x32_bf16(a0, b0, acc00, 0, 0, 0);
        acc01 = __builtin_amdgcn_mfma_f32_16x16x32_bf16(a1, b0, acc01, 0, 0, 0);
        acc10 = __builtin_amdgcn_mfma_f32_16x16x32_bf16(a0, b1, acc10, 0, 0, 0);
        acc11 = __builtin_amdgcn_mfma_f32_16x16x32_bf16(a1, b1, acc11, 0, 0, 0);
    }

    int col0 = y * 128 + wave * 32 + lr;
    #pragma unroll
    for (int m = 0; m < 2; ++m) {
        #pragma unroll
        for (int j = 0; j < 4; ++j) {
            int tl = m * 16 + jrow + j;
            float w = s_w[tl];
            if (w == 0.f) continue;
            float* orow = out + (size_t)s_tok[tl] * DDIM;
            float v0 = m ? acc01[j] : acc00[j];
            float v1 = m ? acc11[j] : acc10[j];
            atomicAdd(orow + col0,      w * v0);
            atomicAdd(orow + col0 + 16, w * v1);
        }
    }
}

extern "C" void kernel_launch(void* const* d_in, const int* in_sizes, int n_in,
                              void* d_out, int out_size, void* d_ws, size_t ws_size,
                              hipStream_t stream) {
    const float* x      = (const float*)d_in[0];
    const float* gate_w = (const float*)d_in[1];
    const float* sg_w   = (const float*)d_in[2];
    const float* su_w   = (const float*)d_in[3];
    const float* sd_w   = (const float*)d_in[4];
    const float* rg_w   = (const float*)d_in[5];
    const float* ru_w   = (const float*)d_in[6];
    const float* rd_w   = (const float*)d_in[7];
    float* out = (float*)d_out;

    char* ws = (char*)d_ws;
    int*   counts    = (int*)(ws + 0);
    int*   perm_t    = (int*)(ws + 1024);
    float* perm_w    = (float*)(ws + 132096);
    float* p_partial = (float*)(ws + 263168);
    int*   topk_i    = (int*)(ws + 295936);
    float* topk_w    = (float*)(ws + 312320);
    unsigned short* xb  = (unsigned short*)(ws + WS_XB);
    unsigned short* w1f = (unsigned short*)(ws + WS_W1F);
    unsigned short* wdf = (unsigned short*)(ws + WS_WDF);
    unsigned short* hbuf= (unsigned short*)(ws + WS_H);

    gate_kernel<<<GBLK, 256, 0, stream>>>(x, gate_w, topk_i, topk_w, p_partial);

    convzero_kernel<<<ZBLK + CBLK, 256, 0, stream>>>(
        x, rg_w, ru_w, sg_w, su_w, rd_w, sd_w,
        (float4*)out, xb, w1f, wdf);

    route_kernel<<<1, 256, 0, stream>>>(topk_i, topk_w, p_partial,
                                        counts, perm_t, perm_w,
                                        out + (size_t)NTOK * DDIM);

    p1_kernel<<<NWORK, 256, 0, stream>>>(xb, w1f, counts, perm_t, hbuf);

    p2_kernel<<<NWORK, 256, 0, stream>>>(hbuf, wdf, counts, perm_t, perm_w, out);
}